// Round 10
// baseline (369.068 us; speedup 1.0000x reference)
//
#include <hip/hip_runtime.h>
#include <math.h>

// ---------------------------------------------------------------------------
// Round 15: base = R10/R14 (verified stable 341.5/342.2us). Single change:
// m-split (MSPLIT=2 via blockIdx.y) on the six C64 k3 convs (r0/r1/c1 at
// levels 0/1/2). They are GRID-limited: level0 512 blocks = 2 blocks/CU
// (8 waves/CU, LDS only 23KB), level1 128 blocks = half the CUs idle,
// level2 16/256 CUs. Split doubles resident blocks (level0 -> 16 waves/CU,
// level1 -> full machine) at the cost of duplicated halo staging (L2-hot).
// Template change is a defaulted param: MSPLIT=1 instantiations (big conv,
// conv_out) keep identical logic. conv_k2/pack untouched.
// Canary: big conv must stay ~49us / VGPR 92. absmax unchanged 0.015625.
// ---------------------------------------------------------------------------

typedef _Float16 f16;
typedef _Float16 f16x8 __attribute__((ext_vector_type(8)));
typedef _Float16 f16x4 __attribute__((ext_vector_type(4)));
typedef float    f32x4 __attribute__((ext_vector_type(4)));

#define PIX 40   // f16 per LDS pixel: 32 payload + 8 pad (80B, 16B-aligned)

// ---- weight packing — single f16 plane ----
__device__ inline void pack_one(const float* __restrict__ w, f16* __restrict__ wp,
                                int Cin, int taps, int CH, int NMT, int e, int lane)
{
    const int gmt = e % NMT;
    const int h   = (e / NMT) % CH;
    const int tap = e / (NMT * CH);
    const int cout = gmt * 16 + (lane & 15);
    const int cin0 = h * 32 + ((lane >> 4) & 3) * 8;
    f16x8 v;
    for (int j = 0; j < 8; ++j)
        v[j] = (f16)w[((size_t)cout * Cin + cin0 + j) * taps + tap];
    *(f16x8*)&wp[((size_t)e * 64 + lane) * 8] = v;
}

// One launch: blocks [0,213) pack all 6 weights (4 entries/block),
// blocks [213,...) pack x f32 [64][64^3] -> f16 [pos][ch] (if x16 != null).
__global__ __launch_bounds__(256) void pack_fused(
    const float* wh, const float* wc0, const float* wr0,
    const float* wr1, const float* wc1, const float* wout,
    f16* ph, f16* pc0, f16* pr0, f16* pr1, f16* pc1, f16* pout,
    const float* x, f16* x16)
{
    const int b = blockIdx.x;
    if (b < 213) {
        const int e    = b * 4 + (threadIdx.x >> 6);
        const int lane = threadIdx.x & 63;
        if      (e < 32)   pack_one(wh,   ph,   32, 8,  1, 4, e,        lane);
        else if (e < 96)   pack_one(wc0,  pc0,  64, 8,  2, 4, e - 32,   lane);
        else if (e < 312)  pack_one(wr0,  pr0,  64, 27, 2, 4, e - 96,   lane);
        else if (e < 528)  pack_one(wr1,  pr1,  64, 27, 2, 4, e - 312,  lane);
        else if (e < 744)  pack_one(wc1,  pc1,  64, 27, 2, 4, e - 528,  lane);
        else               pack_one(wout, pout, 64, 27, 2, 2, e - 744,  lane);
    } else if (x16) {
        const int i   = (b - 213) * 256 + threadIdx.x;   // [0, 64^3*8)
        const int g   = (i >> 3) & 7;
        const int pos = ((i >> 6) << 3) | (i & 7);
        const float* src = x + (size_t)g * 8 * 262144 + pos;
        f16x8 hi;
#pragma unroll
        for (int j = 0; j < 8; ++j) hi[j] = (f16)src[(size_t)j * 262144];
        *(f16x8*)&x16[(size_t)pos * 64 + g * 8] = hi;
    }
}

// Octant swizzle for XCD L2 locality.
template<int NXC, int NYC, int NZC>
__device__ inline void tile_coords(int bid, int& xc, int& yb, int& zb)
{
    if ((NXC % 2 == 0) && (NYC % 2 == 0) && (NZC % 2 == 0) && (NXC*NYC*NZC >= 64)) {
        const int o = bid & 7, j = bid >> 3;
        constexpr int HX = NXC / 2, HY = NYC / 2;
        xc = (j % HX) + (o & 1) * HX;
        yb = ((j / HX) % HY) + ((o >> 1) & 1) * HY;
        zb = (j / (HX * HY)) + (o >> 2) * (NZC / 2);
    } else {
        xc = bid % NXC;
        yb = (bid / NXC) % NYC;
        zb = bid / (NXC * NYC);
    }
}

// ---------------- k3 s1 SAME conv, Cin=64 ----------------
// 4 waves = 2 n-groups x 2 m-groups. Each wave: NT n-tiles (16 px each),
// MTW = (NMT/MSPLIT)/2 m-tiles. Block px = 2*NT*16 = TX*TY*TZ.
// MSPLIT>1: blockIdx.y selects a cout-range (m-split for occupancy).
template<int S, int TX, int TY, int TZ, int NT, int NMT, int ACT_C, bool SRCF32,
         int MSPLIT = 1>
__global__ __launch_bounds__(256) void conv_k3(
    const void* __restrict__ in_, const f16* __restrict__ wp,
    const f16* __restrict__ addsrc, f16* __restrict__ act_out,
    float* __restrict__ f32_out, int relu, float scale)
{
    constexpr int S2 = S * S, S3 = S2 * S;
    constexpr int XP = TX + 2, YP = TY + 2, ZP = TZ + 2;
    constexpr int NPX = XP * YP * ZP;
    constexpr int NXC = S / TX, NYC = S / TY, NZC = S / TZ;
    constexpr int CH = 2;
    constexpr int NMTE = NMT / MSPLIT;
    constexpr int MTW = NMTE / 2;
    static_assert(TX * TY * TZ == 2 * NT * 16, "tile/wave mismatch");
    static_assert(NMTE >= 2, "m-split too deep");
    __shared__ __align__(16) f16 sm[NPX * PIX];

    int xc, yb, zb;
    tile_coords<NXC, NYC, NZC>(blockIdx.x, xc, yb, zb);
    const int x0 = xc * TX, y0 = yb * TY, z0 = zb * TZ;
    const int mb = (MSPLIT > 1) ? (int)blockIdx.y * NMTE : 0;

    const int tid  = threadIdx.x;
    const int lane = tid & 63;
    const int wave = tid >> 6;
    const int i15  = lane & 15, quad = (lane >> 4) & 3;
    const int ng = wave & 1, mh = wave >> 1;

    int lx[NT], ly[NT], lz[NT];
#pragma unroll
    for (int t = 0; t < NT; ++t) {
        const int p = (ng * NT + t) * 16 + i15;
        lx[t] = p % TX; ly[t] = (p / TX) % TY; lz[t] = p / (TX * TY);
    }

    f32x4 acc[NT][MTW];
#pragma unroll
    for (int t = 0; t < NT; ++t)
#pragma unroll
        for (int m = 0; m < MTW; ++m) { f32x4 z = {0.f,0.f,0.f,0.f}; acc[t][m] = z; }

    for (int h = 0; h < CH; ++h) {
        __syncthreads();
        if (SRCF32) {
            const float* src = (const float*)in_;
            for (int it = tid; it < NPX * 4; it += 256) {
                const int xp = it % XP;
                const int rem = it / XP;
                const int row = rem % (YP * ZP);
                const int cc = rem / (YP * ZP);       // 0..3
                const int zr = row / YP, yr = row % YP;
                const int pz = z0 + zr - 1, py = y0 + yr - 1, px = x0 + xp - 1;
                const bool ok = (unsigned)pz < (unsigned)S && (unsigned)py < (unsigned)S
                             && (unsigned)px < (unsigned)S;
                f16x8 v;
                if (ok) {
                    const size_t pos = (size_t)(pz * S2 + py * S + px);
                    const int cbase = h * 32 + cc * 8;
#pragma unroll
                    for (int j = 0; j < 8; ++j)
                        v[j] = (f16)src[(size_t)(cbase + j) * S3 + pos];
                } else {
#pragma unroll
                    for (int j = 0; j < 8; ++j) v[j] = (f16)0.f;
                }
                *(f16x8*)&sm[(row * XP + xp) * PIX + cc * 8] = v;
            }
        } else {
            const f16* src = (const f16*)in_;
            for (int it = tid; it < NPX * 4; it += 256) {
                const int cc = it & 3;
                const int pxl = it >> 2;
                const int xp = pxl % XP;
                const int row = pxl / XP;
                const int zr = row / YP, yr = row % YP;
                const int pz = z0 + zr - 1, py = y0 + yr - 1, px = x0 + xp - 1;
                const bool ok = (unsigned)pz < (unsigned)S && (unsigned)py < (unsigned)S
                             && (unsigned)px < (unsigned)S;
                f16x8 v;
                if (ok) {
                    const size_t pos = (size_t)(pz * S2 + py * S + px);
                    v = *(const f16x8*)&src[pos * 64 + h * 32 + cc * 8];
                } else {
#pragma unroll
                    for (int j = 0; j < 8; ++j) v[j] = (f16)0.f;
                }
                *(f16x8*)&sm[(row * XP + xp) * PIX + cc * 8] = v;
            }
        }
        __syncthreads();

        for (int dz = 0; dz < 3; ++dz) {
#pragma unroll
            for (int dy = 0; dy < 3; ++dy) {
#pragma unroll
                for (int dx = 0; dx < 3; ++dx) {
                    const int tap = dz * 9 + dy * 3 + dx;
                    f16x8 aw[MTW];
#pragma unroll
                    for (int m = 0; m < MTW; ++m) {
                        const int gm = mb + mh * MTW + m;
                        aw[m] = *(const f16x8*)&wp[((size_t)((tap * CH + h) * NMT + gm)) * 512 + lane * 8];
                    }
#pragma unroll
                    for (int t = 0; t < NT; ++t) {
                        const int pix = ((lz[t] + dz) * YP + ly[t] + dy) * XP + lx[t] + dx;
                        const f16x8 bh = *(const f16x8*)&sm[pix * PIX + quad * 8];
#pragma unroll
                        for (int m = 0; m < MTW; ++m)
                            acc[t][m] = __builtin_amdgcn_mfma_f32_16x16x32_f16(aw[m], bh, acc[t][m], 0, 0, 0);
                    }
                }
            }
        }
    }

    // epilogue: C/D layout col(=pos)=lane&15, row(=cout_local)=quad*4+r
#pragma unroll
    for (int t = 0; t < NT; ++t) {
        const int pg = (z0 + lz[t]) * S2 + (y0 + ly[t]) * S + x0 + lx[t];
#pragma unroll
        for (int m = 0; m < MTW; ++m) {
            const int gm = mb + mh * MTW + m;
            float a[4];
#pragma unroll
            for (int r = 0; r < 4; ++r) a[r] = acc[t][m][r];
            if (addsrc) {
                const f16x4 ah = *(const f16x4*)&addsrc[(size_t)pg * 64 + gm * 16 + quad * 4];
#pragma unroll
                for (int r = 0; r < 4; ++r) a[r] += (float)ah[r];
            }
            if (relu) {
#pragma unroll
                for (int r = 0; r < 4; ++r) a[r] = fmaxf(a[r], 0.f);
            }
            if (act_out) {
                f16x4 hi;
#pragma unroll
                for (int r = 0; r < 4; ++r) hi[r] = (f16)a[r];
                *(f16x4*)&act_out[(size_t)pg * ACT_C + gm * 16 + quad * 4] = hi;
            }
            if (f32_out) {
#pragma unroll
                for (int r = 0; r < 4; ++r)
                    f32_out[(size_t)(gm * 16 + quad * 4 + r) * S3 + pg] = a[r] * scale;
            }
        }
    }
}

// ---------------- k2 s2 VALID conv ----------------
// 32 out px per block (2 ngroups x 16), m-split. Even/odd x-interleaved LDS
// slots keep stride-2 reads conflict-free.
template<int So, int TX, int TY, int TZ, int NMT, int CH, bool SRCF32, int SRC_C, bool GATE>
__global__ __launch_bounds__(256) void conv_k2(
    const void* __restrict__ in_, const f16* __restrict__ wp,
    f16* __restrict__ act_out, f16* __restrict__ cx, float src_scale)
{
    constexpr int So2 = So * So;
    constexpr int Si = 2 * So, Si2 = Si * Si, Si3 = Si2 * Si;
    constexpr int XI = 2 * TX, YI = 2 * TY, ZI = 2 * TZ;
    constexpr int NPX = XI * YI * ZI;
    constexpr int NXC = So / TX, NYC = So / TY, NZC = So / TZ;
    constexpr int MTW = NMT / 2;
    static_assert(TX * TY * TZ == 32, "k2 tile must be 32 px");
    __shared__ __align__(16) f16 sm[NPX * PIX];

    int xc, yb, zb;
    tile_coords<NXC, NYC, NZC>(blockIdx.x, xc, yb, zb);
    const int x0 = xc * TX, y0 = yb * TY, z0 = zb * TZ;

    const int tid  = threadIdx.x;
    const int lane = tid & 63;
    const int wave = tid >> 6;
    const int i15  = lane & 15, quad = (lane >> 4) & 3;
    const int nt = wave & 1, mh = wave >> 1;
    const int p = nt * 16 + i15;
    const int lx = p % TX, ly = (p / TX) % TY, lz = p / (TX * TY);

    f32x4 acc[MTW];
#pragma unroll
    for (int m = 0; m < MTW; ++m) { f32x4 z = {0.f,0.f,0.f,0.f}; acc[m] = z; }

    for (int h = 0; h < CH; ++h) {
        __syncthreads();
        if (SRCF32) {
            const float* src = (const float*)in_;
            for (int it = tid; it < NPX * 4; it += 256) {
                const int xp = it % XI;
                const int rem = it / XI;
                const int row = rem % (YI * ZI);
                const int cc = rem / (YI * ZI);       // 0..3
                const int zr = row / YI, yr = row % YI;
                const size_t pos = (size_t)((z0 * 2 + zr) * Si2 + (y0 * 2 + yr) * Si + x0 * 2 + xp);
                const int cbase = h * 32 + cc * 8;
                f16x8 v;
#pragma unroll
                for (int j = 0; j < 8; ++j)
                    v[j] = (f16)(src[(size_t)(cbase + j) * Si3 + pos] * src_scale);
                const int slot = (xp >> 1) + (xp & 1) * TX;
                *(f16x8*)&sm[(row * XI + slot) * PIX + cc * 8] = v;
            }
        } else {
            const f16* src = (const f16*)in_;
            for (int it = tid; it < NPX * 4; it += 256) {
                const int cc = it & 3;
                const int pxl = it >> 2;
                const int xp = pxl % XI;
                const int row = pxl / XI;
                const int zr = row / YI, yr = row % YI;
                const size_t pos = (size_t)((z0 * 2 + zr) * Si2 + (y0 * 2 + yr) * Si + x0 * 2 + xp);
                f16x8 v = *(const f16x8*)&src[pos * SRC_C + h * 32 + cc * 8];
                const int slot = (xp >> 1) + (xp & 1) * TX;
                *(f16x8*)&sm[(row * XI + slot) * PIX + cc * 8] = v;
            }
        }
        __syncthreads();

#pragma unroll
        for (int dz = 0; dz < 2; ++dz) {
#pragma unroll
            for (int dy = 0; dy < 2; ++dy) {
#pragma unroll
                for (int dx = 0; dx < 2; ++dx) {
                    const int tap = dz * 4 + dy * 2 + dx;
                    const int pix = ((2 * lz + dz) * YI + 2 * ly + dy) * XI + lx + dx * TX;
                    const f16x8 bh = *(const f16x8*)&sm[pix * PIX + quad * 8];
#pragma unroll
                    for (int m = 0; m < MTW; ++m) {
                        const int gm = mh * MTW + m;
                        const f16x8 aw = *(const f16x8*)&wp[((size_t)((tap * CH + h) * NMT + gm)) * 512 + lane * 8];
                        acc[m] = __builtin_amdgcn_mfma_f32_16x16x32_f16(aw, bh, acc[m], 0, 0, 0);
                    }
                }
            }
        }
    }

    const int pg = (z0 + lz) * So2 + (y0 + ly) * So + x0 + lx;
#pragma unroll
    for (int m = 0; m < MTW; ++m) {
        const int gm = mh * MTW + m;
        if (GATE) {
            f16x4 c4 = *(const f16x4*)&cx[(size_t)pg * 64 + gm * 16 + quad * 4];
            f16x4 n4;
#pragma unroll
            for (int r = 0; r < 4; ++r) {
                const float g = 1.0f / (1.0f + expf(-fmaxf(acc[m][r], 0.f)));
                n4[r] = (f16)((float)c4[r] * g);
            }
            *(f16x4*)&cx[(size_t)pg * 64 + gm * 16 + quad * 4] = n4;
        } else {
            f16x4 hi;
#pragma unroll
            for (int r = 0; r < 4; ++r) hi[r] = (f16)fmaxf(acc[m][r], 0.f); // ConvBlock relu
            *(f16x4*)&act_out[(size_t)pg * 64 + gm * 16 + quad * 4] = hi;
        }
    }
}

extern "C" void kernel_launch(void* const* d_in, const int* in_sizes, int n_in,
                              void* d_out, int out_size, void* d_ws, size_t ws_size,
                              hipStream_t stream)
{
    const float* x     = (const float*)d_in[0];
    const float* w_h   = (const float*)d_in[1];
    const float* w_c0  = (const float*)d_in[2];
    const float* w_r0  = (const float*)d_in[3];
    const float* w_r1  = (const float*)d_in[4];
    const float* w_c1  = (const float*)d_in[5];
    const float* w_out = (const float*)d_in[6];
    float* out = (float*)d_out;
    f16* ws = (f16*)d_ws;

    // ws layout (f16 units) — single-plane weights
    size_t o = 0;
    f16* wp_h   = ws + o; o += (size_t)8 * 1 * 4 * 512;     // 32 entries
    f16* wp_c0  = ws + o; o += (size_t)8 * 2 * 4 * 512;     // 64
    f16* wp_r0  = ws + o; o += (size_t)27 * 2 * 4 * 512;    // 216
    f16* wp_r1  = ws + o; o += (size_t)27 * 2 * 4 * 512;    // 216
    f16* wp_c1  = ws + o; o += (size_t)27 * 2 * 4 * 512;    // 216
    f16* wp_out = ws + o; o += (size_t)27 * 2 * 2 * 512;    // 108
    const size_t ABUF = (size_t)32 * 32 * 32 * 64;          // C=64 act, 32^3
    f16* y_buf  = ws + o; o += ABUF;
    f16* t_buf  = ws + o; o += ABUF;
    f16* cx     = ws + o; o += ABUF;
    f16* hx_act = ws + o; o += (size_t)32 * 32 * 32 * 32;   // C=32 act, 32^3
    // fast-path buffers
    f16* x16    = ws + o; const size_t o_x16  = o + (size_t)64 * 64 * 64 * 64;
    f16* hx0a   = ws + o_x16; const size_t o_end = o_x16 + (size_t)64 * 64 * 64 * 32;
    const bool fast = ws_size >= o_end * sizeof(f16);

    size_t offs[4];
    offs[0] = 0;
    offs[1] = offs[0] + (size_t)32 * 64 * 64 * 64;
    offs[2] = offs[1] + (size_t)32 * 32 * 32 * 32;
    offs[3] = offs[2] + (size_t)32 * 16 * 16 * 16;

    const dim3 blk(256);

    // one merged pack launch: 213 weight blocks (+8192 x blocks on fast path)
    pack_fused<<<dim3(fast ? 8405 : 213), blk, 0, stream>>>(
        w_h, w_c0, w_r0, w_r1, w_c1, w_out,
        wp_h, wp_c0, wp_r0, wp_r1, wp_c1, wp_out,
        x, fast ? x16 : nullptr);

    if (fast) {
        // hx0 = 0.5 * conv_out(x) @64^3. Tile 16x4x4 (NT=8), f16 src,
        // also emit unscaled hx0 act (C=32) for the level-0 gate.
        conv_k3<64, 16, 4, 4, 8, 2, 32, false><<<dim3(1024), blk, 0, stream>>>(
            x16, wp_out, nullptr, hx0a, out + offs[0], 0, 0.5f);

        // ---- level 0: 64 -> 32 ----  (C64 k3s m-split: grid (512,2))
        conv_k2<32, 16, 2, 1, 4, 2, false, 64, false><<<dim3(1024), blk, 0, stream>>>(
            x16, wp_c0, y_buf, nullptr, 1.0f);
        conv_k3<32, 16, 2, 2, 2, 4, 64, false, 2><<<dim3(512, 2), blk, 0, stream>>>(
            y_buf, wp_r0, nullptr, t_buf, nullptr, 1, 1.0f);
        conv_k3<32, 16, 2, 2, 2, 4, 64, false, 2><<<dim3(512, 2), blk, 0, stream>>>(
            t_buf, wp_r1, y_buf, y_buf, nullptr, 0, 1.0f);
        conv_k3<32, 16, 2, 2, 2, 4, 64, false, 2><<<dim3(512, 2), blk, 0, stream>>>(
            y_buf, wp_c1, nullptr, cx, nullptr, 0, 1.0f);
        conv_k2<32, 16, 2, 1, 4, 1, false, 32, true><<<dim3(1024), blk, 0, stream>>>(
            hx0a, wp_h, nullptr, cx, 1.0f);
        conv_k3<32, 16, 2, 2, 2, 2, 32, false><<<dim3(512), blk, 0, stream>>>(
            cx, wp_out, nullptr, hx_act, out + offs[1], 0, 0.5f);
    } else {
        // fallback: f32-source path (same numerics).
        conv_k3<64, 16, 4, 2, 4, 2, 32, true><<<dim3(2048), blk, 0, stream>>>(
            x, wp_out, nullptr, nullptr, out + offs[0], 0, 0.5f);

        conv_k2<32, 16, 2, 1, 4, 2, true, 64, false><<<dim3(1024), blk, 0, stream>>>(
            x, wp_c0, y_buf, nullptr, 1.0f);
        conv_k3<32, 16, 2, 2, 2, 4, 64, false, 2><<<dim3(512, 2), blk, 0, stream>>>(
            y_buf, wp_r0, nullptr, t_buf, nullptr, 1, 1.0f);
        conv_k3<32, 16, 2, 2, 2, 4, 64, false, 2><<<dim3(512, 2), blk, 0, stream>>>(
            t_buf, wp_r1, y_buf, y_buf, nullptr, 0, 1.0f);
        conv_k3<32, 16, 2, 2, 2, 4, 64, false, 2><<<dim3(512, 2), blk, 0, stream>>>(
            y_buf, wp_c1, nullptr, cx, nullptr, 0, 1.0f);
        conv_k2<32, 16, 2, 1, 4, 1, true, 32, true><<<dim3(1024), blk, 0, stream>>>(
            out + offs[0], wp_h, nullptr, cx, 2.0f);
        conv_k3<32, 16, 2, 2, 2, 2, 32, false><<<dim3(512), blk, 0, stream>>>(
            cx, wp_out, nullptr, hx_act, out + offs[1], 0, 0.5f);
    }

    // ---- level 1: 32 -> 16 ----  (C64 k3s m-split: grid (128,2))
    conv_k2<16, 16, 2, 1, 4, 2, false, 64, false><<<dim3(128), blk, 0, stream>>>(
        cx, wp_c0, y_buf, nullptr, 1.0f);
    conv_k3<16, 16, 2, 1, 1, 4, 64, false, 2><<<dim3(128, 2), blk, 0, stream>>>(
        y_buf, wp_r0, nullptr, t_buf, nullptr, 1, 1.0f);
    conv_k3<16, 16, 2, 1, 1, 4, 64, false, 2><<<dim3(128, 2), blk, 0, stream>>>(
        t_buf, wp_r1, y_buf, y_buf, nullptr, 0, 1.0f);
    conv_k3<16, 16, 2, 1, 1, 4, 64, false, 2><<<dim3(128, 2), blk, 0, stream>>>(
        y_buf, wp_c1, nullptr, cx, nullptr, 0, 1.0f);
    conv_k2<16, 16, 2, 1, 4, 1, false, 32, true><<<dim3(128), blk, 0, stream>>>(
        hx_act, wp_h, nullptr, cx, 1.0f);
    conv_k3<16, 16, 2, 1, 1, 2, 32, false><<<dim3(128), blk, 0, stream>>>(
        cx, wp_out, nullptr, hx_act, out + offs[2], 0, 0.5f);

    // ---- level 2: 16 -> 8 ----  (C64 k3s m-split: grid (16,2))
    conv_k2<8, 8, 4, 1, 4, 2, false, 64, false><<<dim3(16), blk, 0, stream>>>(
        cx, wp_c0, y_buf, nullptr, 1.0f);
    conv_k3<8, 8, 4, 1, 1, 4, 64, false, 2><<<dim3(16, 2), blk, 0, stream>>>(
        y_buf, wp_r0, nullptr, t_buf, nullptr, 1, 1.0f);
    conv_k3<8, 8, 4, 1, 1, 4, 64, false, 2><<<dim3(16, 2), blk, 0, stream>>>(
        t_buf, wp_r1, y_buf, y_buf, nullptr, 0, 1.0f);
    conv_k3<8, 8, 4, 1, 1, 4, 64, false, 2><<<dim3(16, 2), blk, 0, stream>>>(
        y_buf, wp_c1, nullptr, cx, nullptr, 0, 1.0f);
    conv_k2<8, 8, 4, 1, 4, 1, false, 32, true><<<dim3(16), blk, 0, stream>>>(
        hx_act, wp_h, nullptr, cx, 1.0f);
    conv_k3<8, 8, 4, 1, 1, 2, 32, false><<<dim3(16), blk, 0, stream>>>(
        cx, wp_out, nullptr, nullptr, out + offs[3], 0, 0.5f);
}

// Round 11
// 362.928 us; speedup vs baseline: 1.0169x; 1.0169x over previous
//
#include <hip/hip_runtime.h>
#include <math.h>

// ---------------------------------------------------------------------------
// Round 16: base = R14 (verified 342us). R15 m-split regressed +27us
// (duplicated staging > occupancy gain; canary clean -> attribution exact).
// This round removes work instead of adding it: FUSECH on the nine SMALL
// k3 dispatches — merge the two channel-half passes into ONE stage (all 64
// ch, 2x loads in flight, fully contiguous 128B/px reads) + ONE barrier +
// ONE 54-tap compute run (was 3 barriers, 2 short phases each). LDS/px
// doubles to PIX2=72 (144B stride = 36 dwords = 4 mod 32, same free 2-way
// bank class): level-0 C64 k3 41.5KB -> still 3 blocks/CU. Big conv keeps
// 2-pass (93KB would be 1 block/CU — R6 lesson). conv_k2/pack unchanged.
// Canary: big conv ~49us / VGPR 92. absmax ~0.015625 (h-order rounding
// delta negligible vs f16 quant floor).
// ---------------------------------------------------------------------------

typedef _Float16 f16;
typedef _Float16 f16x8 __attribute__((ext_vector_type(8)));
typedef _Float16 f16x4 __attribute__((ext_vector_type(4)));
typedef float    f32x4 __attribute__((ext_vector_type(4)));

#define PIX 40   // f16 per LDS pixel: 32 payload + 8 pad (80B, 16B-aligned)

// ---- weight packing — single f16 plane ----
__device__ inline void pack_one(const float* __restrict__ w, f16* __restrict__ wp,
                                int Cin, int taps, int CH, int NMT, int e, int lane)
{
    const int gmt = e % NMT;
    const int h   = (e / NMT) % CH;
    const int tap = e / (NMT * CH);
    const int cout = gmt * 16 + (lane & 15);
    const int cin0 = h * 32 + ((lane >> 4) & 3) * 8;
    f16x8 v;
    for (int j = 0; j < 8; ++j)
        v[j] = (f16)w[((size_t)cout * Cin + cin0 + j) * taps + tap];
    *(f16x8*)&wp[((size_t)e * 64 + lane) * 8] = v;
}

// One launch: blocks [0,213) pack all 6 weights (4 entries/block),
// blocks [213,...) pack x f32 [64][64^3] -> f16 [pos][ch] (if x16 != null).
__global__ __launch_bounds__(256) void pack_fused(
    const float* wh, const float* wc0, const float* wr0,
    const float* wr1, const float* wc1, const float* wout,
    f16* ph, f16* pc0, f16* pr0, f16* pr1, f16* pc1, f16* pout,
    const float* x, f16* x16)
{
    const int b = blockIdx.x;
    if (b < 213) {
        const int e    = b * 4 + (threadIdx.x >> 6);
        const int lane = threadIdx.x & 63;
        if      (e < 32)   pack_one(wh,   ph,   32, 8,  1, 4, e,        lane);
        else if (e < 96)   pack_one(wc0,  pc0,  64, 8,  2, 4, e - 32,   lane);
        else if (e < 312)  pack_one(wr0,  pr0,  64, 27, 2, 4, e - 96,   lane);
        else if (e < 528)  pack_one(wr1,  pr1,  64, 27, 2, 4, e - 312,  lane);
        else if (e < 744)  pack_one(wc1,  pc1,  64, 27, 2, 4, e - 528,  lane);
        else               pack_one(wout, pout, 64, 27, 2, 2, e - 744,  lane);
    } else if (x16) {
        const int i   = (b - 213) * 256 + threadIdx.x;   // [0, 64^3*8)
        const int g   = (i >> 3) & 7;
        const int pos = ((i >> 6) << 3) | (i & 7);
        const float* src = x + (size_t)g * 8 * 262144 + pos;
        f16x8 hi;
#pragma unroll
        for (int j = 0; j < 8; ++j) hi[j] = (f16)src[(size_t)j * 262144];
        *(f16x8*)&x16[(size_t)pos * 64 + g * 8] = hi;
    }
}

// Octant swizzle for XCD L2 locality.
template<int NXC, int NYC, int NZC>
__device__ inline void tile_coords(int bid, int& xc, int& yb, int& zb)
{
    if ((NXC % 2 == 0) && (NYC % 2 == 0) && (NZC % 2 == 0) && (NXC*NYC*NZC >= 64)) {
        const int o = bid & 7, j = bid >> 3;
        constexpr int HX = NXC / 2, HY = NYC / 2;
        xc = (j % HX) + (o & 1) * HX;
        yb = ((j / HX) % HY) + ((o >> 1) & 1) * HY;
        zb = (j / (HX * HY)) + (o >> 2) * (NZC / 2);
    } else {
        xc = bid % NXC;
        yb = (bid / NXC) % NYC;
        zb = bid / (NXC * NYC);
    }
}

// ---------------- k3 s1 SAME conv, Cin=64 ----------------
// 4 waves = 2 n-groups x 2 m-groups. Each wave: NT n-tiles (16 px each),
// MTW = NMT/2 m-tiles. Block px = 2*NT*16 = TX*TY*TZ.
// FUSECH: stage all 64 channels once (PIX2=72), 1 barrier, 54-tap compute.
template<int S, int TX, int TY, int TZ, int NT, int NMT, int ACT_C, bool SRCF32,
         bool FUSECH = false>
__global__ __launch_bounds__(256) void conv_k3(
    const void* __restrict__ in_, const f16* __restrict__ wp,
    const f16* __restrict__ addsrc, f16* __restrict__ act_out,
    float* __restrict__ f32_out, int relu, float scale)
{
    constexpr int S2 = S * S, S3 = S2 * S;
    constexpr int XP = TX + 2, YP = TY + 2, ZP = TZ + 2;
    constexpr int NPX = XP * YP * ZP;
    constexpr int NXC = S / TX, NYC = S / TY, NZC = S / TZ;
    constexpr int CH = 2;
    constexpr int MTW = NMT / 2;
    constexpr int PIXE = FUSECH ? 72 : PIX;   // 72: 64 payload + 8 pad
    static_assert(TX * TY * TZ == 2 * NT * 16, "tile/wave mismatch");
    static_assert(!(FUSECH && SRCF32), "fused staging needs f16 source");
    __shared__ __align__(16) f16 sm[NPX * PIXE];

    int xc, yb, zb;
    tile_coords<NXC, NYC, NZC>(blockIdx.x, xc, yb, zb);
    const int x0 = xc * TX, y0 = yb * TY, z0 = zb * TZ;

    const int tid  = threadIdx.x;
    const int lane = tid & 63;
    const int wave = tid >> 6;
    const int i15  = lane & 15, quad = (lane >> 4) & 3;
    const int ng = wave & 1, mh = wave >> 1;

    int lx[NT], ly[NT], lz[NT];
#pragma unroll
    for (int t = 0; t < NT; ++t) {
        const int p = (ng * NT + t) * 16 + i15;
        lx[t] = p % TX; ly[t] = (p / TX) % TY; lz[t] = p / (TX * TY);
    }

    f32x4 acc[NT][MTW];
#pragma unroll
    for (int t = 0; t < NT; ++t)
#pragma unroll
        for (int m = 0; m < MTW; ++m) { f32x4 z = {0.f,0.f,0.f,0.f}; acc[t][m] = z; }

    if constexpr (FUSECH) {
        // ---- single stage: all 64 channels, fully contiguous 128B/px ----
        const f16* src = (const f16*)in_;
        for (int it = tid; it < NPX * 8; it += 256) {
            const int cc = it & 7;
            const int pxl = it >> 3;
            const int xp = pxl % XP;
            const int row = pxl / XP;
            const int zr = row / YP, yr = row % YP;
            const int pz = z0 + zr - 1, py = y0 + yr - 1, px = x0 + xp - 1;
            const bool ok = (unsigned)pz < (unsigned)S && (unsigned)py < (unsigned)S
                         && (unsigned)px < (unsigned)S;
            f16x8 v;
            if (ok) {
                const size_t pos = (size_t)(pz * S2 + py * S + px);
                v = *(const f16x8*)&src[pos * 64 + cc * 8];
            } else {
#pragma unroll
                for (int j = 0; j < 8; ++j) v[j] = (f16)0.f;
            }
            *(f16x8*)&sm[(row * XP + xp) * PIXE + cc * 8] = v;
        }
        __syncthreads();

        // ---- one 54-tap compute run (h inner) ----
        for (int dz = 0; dz < 3; ++dz) {
#pragma unroll
            for (int dy = 0; dy < 3; ++dy) {
#pragma unroll
                for (int dx = 0; dx < 3; ++dx) {
                    const int tap = dz * 9 + dy * 3 + dx;
#pragma unroll
                    for (int h = 0; h < CH; ++h) {
                        f16x8 aw[MTW];
#pragma unroll
                        for (int m = 0; m < MTW; ++m) {
                            const int gm = mh * MTW + m;
                            aw[m] = *(const f16x8*)&wp[((size_t)((tap * CH + h) * NMT + gm)) * 512 + lane * 8];
                        }
#pragma unroll
                        for (int t = 0; t < NT; ++t) {
                            const int pix = ((lz[t] + dz) * YP + ly[t] + dy) * XP + lx[t] + dx;
                            const f16x8 bh = *(const f16x8*)&sm[pix * PIXE + h * 32 + quad * 8];
#pragma unroll
                            for (int m = 0; m < MTW; ++m)
                                acc[t][m] = __builtin_amdgcn_mfma_f32_16x16x32_f16(aw[m], bh, acc[t][m], 0, 0, 0);
                        }
                    }
                }
            }
        }
    } else {
    for (int h = 0; h < CH; ++h) {
        __syncthreads();
        if (SRCF32) {
            const float* src = (const float*)in_;
            for (int it = tid; it < NPX * 4; it += 256) {
                const int xp = it % XP;
                const int rem = it / XP;
                const int row = rem % (YP * ZP);
                const int cc = rem / (YP * ZP);       // 0..3
                const int zr = row / YP, yr = row % YP;
                const int pz = z0 + zr - 1, py = y0 + yr - 1, px = x0 + xp - 1;
                const bool ok = (unsigned)pz < (unsigned)S && (unsigned)py < (unsigned)S
                             && (unsigned)px < (unsigned)S;
                f16x8 v;
                if (ok) {
                    const size_t pos = (size_t)(pz * S2 + py * S + px);
                    const int cbase = h * 32 + cc * 8;
#pragma unroll
                    for (int j = 0; j < 8; ++j)
                        v[j] = (f16)src[(size_t)(cbase + j) * S3 + pos];
                } else {
#pragma unroll
                    for (int j = 0; j < 8; ++j) v[j] = (f16)0.f;
                }
                *(f16x8*)&sm[(row * XP + xp) * PIXE + cc * 8] = v;
            }
        } else {
            const f16* src = (const f16*)in_;
            for (int it = tid; it < NPX * 4; it += 256) {
                const int cc = it & 3;
                const int pxl = it >> 2;
                const int xp = pxl % XP;
                const int row = pxl / XP;
                const int zr = row / YP, yr = row % YP;
                const int pz = z0 + zr - 1, py = y0 + yr - 1, px = x0 + xp - 1;
                const bool ok = (unsigned)pz < (unsigned)S && (unsigned)py < (unsigned)S
                             && (unsigned)px < (unsigned)S;
                f16x8 v;
                if (ok) {
                    const size_t pos = (size_t)(pz * S2 + py * S + px);
                    v = *(const f16x8*)&src[pos * 64 + h * 32 + cc * 8];
                } else {
#pragma unroll
                    for (int j = 0; j < 8; ++j) v[j] = (f16)0.f;
                }
                *(f16x8*)&sm[(row * XP + xp) * PIXE + cc * 8] = v;
            }
        }
        __syncthreads();

        for (int dz = 0; dz < 3; ++dz) {
#pragma unroll
            for (int dy = 0; dy < 3; ++dy) {
#pragma unroll
                for (int dx = 0; dx < 3; ++dx) {
                    const int tap = dz * 9 + dy * 3 + dx;
                    f16x8 aw[MTW];
#pragma unroll
                    for (int m = 0; m < MTW; ++m) {
                        const int gm = mh * MTW + m;
                        aw[m] = *(const f16x8*)&wp[((size_t)((tap * CH + h) * NMT + gm)) * 512 + lane * 8];
                    }
#pragma unroll
                    for (int t = 0; t < NT; ++t) {
                        const int pix = ((lz[t] + dz) * YP + ly[t] + dy) * XP + lx[t] + dx;
                        const f16x8 bh = *(const f16x8*)&sm[pix * PIXE + quad * 8];
#pragma unroll
                        for (int m = 0; m < MTW; ++m)
                            acc[t][m] = __builtin_amdgcn_mfma_f32_16x16x32_f16(aw[m], bh, acc[t][m], 0, 0, 0);
                    }
                }
            }
        }
    }
    }

    // epilogue: C/D layout col(=pos)=lane&15, row(=cout_local)=quad*4+r
#pragma unroll
    for (int t = 0; t < NT; ++t) {
        const int pg = (z0 + lz[t]) * S2 + (y0 + ly[t]) * S + x0 + lx[t];
#pragma unroll
        for (int m = 0; m < MTW; ++m) {
            const int gm = mh * MTW + m;
            float a[4];
#pragma unroll
            for (int r = 0; r < 4; ++r) a[r] = acc[t][m][r];
            if (addsrc) {
                const f16x4 ah = *(const f16x4*)&addsrc[(size_t)pg * 64 + gm * 16 + quad * 4];
#pragma unroll
                for (int r = 0; r < 4; ++r) a[r] += (float)ah[r];
            }
            if (relu) {
#pragma unroll
                for (int r = 0; r < 4; ++r) a[r] = fmaxf(a[r], 0.f);
            }
            if (act_out) {
                f16x4 hi;
#pragma unroll
                for (int r = 0; r < 4; ++r) hi[r] = (f16)a[r];
                *(f16x4*)&act_out[(size_t)pg * ACT_C + gm * 16 + quad * 4] = hi;
            }
            if (f32_out) {
#pragma unroll
                for (int r = 0; r < 4; ++r)
                    f32_out[(size_t)(gm * 16 + quad * 4 + r) * S3 + pg] = a[r] * scale;
            }
        }
    }
}

// ---------------- k2 s2 VALID conv ----------------
// 32 out px per block (2 ngroups x 16), m-split. Even/odd x-interleaved LDS
// slots keep stride-2 reads conflict-free.
template<int So, int TX, int TY, int TZ, int NMT, int CH, bool SRCF32, int SRC_C, bool GATE>
__global__ __launch_bounds__(256) void conv_k2(
    const void* __restrict__ in_, const f16* __restrict__ wp,
    f16* __restrict__ act_out, f16* __restrict__ cx, float src_scale)
{
    constexpr int So2 = So * So;
    constexpr int Si = 2 * So, Si2 = Si * Si, Si3 = Si2 * Si;
    constexpr int XI = 2 * TX, YI = 2 * TY, ZI = 2 * TZ;
    constexpr int NPX = XI * YI * ZI;
    constexpr int NXC = So / TX, NYC = So / TY, NZC = So / TZ;
    constexpr int MTW = NMT / 2;
    static_assert(TX * TY * TZ == 32, "k2 tile must be 32 px");
    __shared__ __align__(16) f16 sm[NPX * PIX];

    int xc, yb, zb;
    tile_coords<NXC, NYC, NZC>(blockIdx.x, xc, yb, zb);
    const int x0 = xc * TX, y0 = yb * TY, z0 = zb * TZ;

    const int tid  = threadIdx.x;
    const int lane = tid & 63;
    const int wave = tid >> 6;
    const int i15  = lane & 15, quad = (lane >> 4) & 3;
    const int nt = wave & 1, mh = wave >> 1;
    const int p = nt * 16 + i15;
    const int lx = p % TX, ly = (p / TX) % TY, lz = p / (TX * TY);

    f32x4 acc[MTW];
#pragma unroll
    for (int m = 0; m < MTW; ++m) { f32x4 z = {0.f,0.f,0.f,0.f}; acc[m] = z; }

    for (int h = 0; h < CH; ++h) {
        __syncthreads();
        if (SRCF32) {
            const float* src = (const float*)in_;
            for (int it = tid; it < NPX * 4; it += 256) {
                const int xp = it % XI;
                const int rem = it / XI;
                const int row = rem % (YI * ZI);
                const int cc = rem / (YI * ZI);       // 0..3
                const int zr = row / YI, yr = row % YI;
                const size_t pos = (size_t)((z0 * 2 + zr) * Si2 + (y0 * 2 + yr) * Si + x0 * 2 + xp);
                const int cbase = h * 32 + cc * 8;
                f16x8 v;
#pragma unroll
                for (int j = 0; j < 8; ++j)
                    v[j] = (f16)(src[(size_t)(cbase + j) * Si3 + pos] * src_scale);
                const int slot = (xp >> 1) + (xp & 1) * TX;
                *(f16x8*)&sm[(row * XI + slot) * PIX + cc * 8] = v;
            }
        } else {
            const f16* src = (const f16*)in_;
            for (int it = tid; it < NPX * 4; it += 256) {
                const int cc = it & 3;
                const int pxl = it >> 2;
                const int xp = pxl % XI;
                const int row = pxl / XI;
                const int zr = row / YI, yr = row % YI;
                const size_t pos = (size_t)((z0 * 2 + zr) * Si2 + (y0 * 2 + yr) * Si + x0 * 2 + xp);
                f16x8 v = *(const f16x8*)&src[pos * SRC_C + h * 32 + cc * 8];
                const int slot = (xp >> 1) + (xp & 1) * TX;
                *(f16x8*)&sm[(row * XI + slot) * PIX + cc * 8] = v;
            }
        }
        __syncthreads();

#pragma unroll
        for (int dz = 0; dz < 2; ++dz) {
#pragma unroll
            for (int dy = 0; dy < 2; ++dy) {
#pragma unroll
                for (int dx = 0; dx < 2; ++dx) {
                    const int tap = dz * 4 + dy * 2 + dx;
                    const int pix = ((2 * lz + dz) * YI + 2 * ly + dy) * XI + lx + dx * TX;
                    const f16x8 bh = *(const f16x8*)&sm[pix * PIX + quad * 8];
#pragma unroll
                    for (int m = 0; m < MTW; ++m) {
                        const int gm = mh * MTW + m;
                        const f16x8 aw = *(const f16x8*)&wp[((size_t)((tap * CH + h) * NMT + gm)) * 512 + lane * 8];
                        acc[m] = __builtin_amdgcn_mfma_f32_16x16x32_f16(aw, bh, acc[m], 0, 0, 0);
                    }
                }
            }
        }
    }

    const int pg = (z0 + lz) * So2 + (y0 + ly) * So + x0 + lx;
#pragma unroll
    for (int m = 0; m < MTW; ++m) {
        const int gm = mh * MTW + m;
        if (GATE) {
            f16x4 c4 = *(const f16x4*)&cx[(size_t)pg * 64 + gm * 16 + quad * 4];
            f16x4 n4;
#pragma unroll
            for (int r = 0; r < 4; ++r) {
                const float g = 1.0f / (1.0f + expf(-fmaxf(acc[m][r], 0.f)));
                n4[r] = (f16)((float)c4[r] * g);
            }
            *(f16x4*)&cx[(size_t)pg * 64 + gm * 16 + quad * 4] = n4;
        } else {
            f16x4 hi;
#pragma unroll
            for (int r = 0; r < 4; ++r) hi[r] = (f16)fmaxf(acc[m][r], 0.f); // ConvBlock relu
            *(f16x4*)&act_out[(size_t)pg * 64 + gm * 16 + quad * 4] = hi;
        }
    }
}

extern "C" void kernel_launch(void* const* d_in, const int* in_sizes, int n_in,
                              void* d_out, int out_size, void* d_ws, size_t ws_size,
                              hipStream_t stream)
{
    const float* x     = (const float*)d_in[0];
    const float* w_h   = (const float*)d_in[1];
    const float* w_c0  = (const float*)d_in[2];
    const float* w_r0  = (const float*)d_in[3];
    const float* w_r1  = (const float*)d_in[4];
    const float* w_c1  = (const float*)d_in[5];
    const float* w_out = (const float*)d_in[6];
    float* out = (float*)d_out;
    f16* ws = (f16*)d_ws;

    // ws layout (f16 units) — single-plane weights
    size_t o = 0;
    f16* wp_h   = ws + o; o += (size_t)8 * 1 * 4 * 512;     // 32 entries
    f16* wp_c0  = ws + o; o += (size_t)8 * 2 * 4 * 512;     // 64
    f16* wp_r0  = ws + o; o += (size_t)27 * 2 * 4 * 512;    // 216
    f16* wp_r1  = ws + o; o += (size_t)27 * 2 * 4 * 512;    // 216
    f16* wp_c1  = ws + o; o += (size_t)27 * 2 * 4 * 512;    // 216
    f16* wp_out = ws + o; o += (size_t)27 * 2 * 2 * 512;    // 108
    const size_t ABUF = (size_t)32 * 32 * 32 * 64;          // C=64 act, 32^3
    f16* y_buf  = ws + o; o += ABUF;
    f16* t_buf  = ws + o; o += ABUF;
    f16* cx     = ws + o; o += ABUF;
    f16* hx_act = ws + o; o += (size_t)32 * 32 * 32 * 32;   // C=32 act, 32^3
    // fast-path buffers
    f16* x16    = ws + o; const size_t o_x16  = o + (size_t)64 * 64 * 64 * 64;
    f16* hx0a   = ws + o_x16; const size_t o_end = o_x16 + (size_t)64 * 64 * 64 * 32;
    const bool fast = ws_size >= o_end * sizeof(f16);

    size_t offs[4];
    offs[0] = 0;
    offs[1] = offs[0] + (size_t)32 * 64 * 64 * 64;
    offs[2] = offs[1] + (size_t)32 * 32 * 32 * 32;
    offs[3] = offs[2] + (size_t)32 * 16 * 16 * 16;

    const dim3 blk(256);

    // one merged pack launch: 213 weight blocks (+8192 x blocks on fast path)
    pack_fused<<<dim3(fast ? 8405 : 213), blk, 0, stream>>>(
        w_h, w_c0, w_r0, w_r1, w_c1, w_out,
        wp_h, wp_c0, wp_r0, wp_r1, wp_c1, wp_out,
        x, fast ? x16 : nullptr);

    if (fast) {
        // hx0 = 0.5 * conv_out(x) @64^3. Tile 16x4x4 (NT=8), f16 src,
        // also emit unscaled hx0 act (C=32) for the level-0 gate.
        conv_k3<64, 16, 4, 4, 8, 2, 32, false><<<dim3(1024), blk, 0, stream>>>(
            x16, wp_out, nullptr, hx0a, out + offs[0], 0, 0.5f);

        // ---- level 0: 64 -> 32 ----  (small k3s: FUSECH)
        conv_k2<32, 16, 2, 1, 4, 2, false, 64, false><<<dim3(1024), blk, 0, stream>>>(
            x16, wp_c0, y_buf, nullptr, 1.0f);
        conv_k3<32, 16, 2, 2, 2, 4, 64, false, true><<<dim3(512), blk, 0, stream>>>(
            y_buf, wp_r0, nullptr, t_buf, nullptr, 1, 1.0f);
        conv_k3<32, 16, 2, 2, 2, 4, 64, false, true><<<dim3(512), blk, 0, stream>>>(
            t_buf, wp_r1, y_buf, y_buf, nullptr, 0, 1.0f);
        conv_k3<32, 16, 2, 2, 2, 4, 64, false, true><<<dim3(512), blk, 0, stream>>>(
            y_buf, wp_c1, nullptr, cx, nullptr, 0, 1.0f);
        conv_k2<32, 16, 2, 1, 4, 1, false, 32, true><<<dim3(1024), blk, 0, stream>>>(
            hx0a, wp_h, nullptr, cx, 1.0f);
        conv_k3<32, 16, 2, 2, 2, 2, 32, false, true><<<dim3(512), blk, 0, stream>>>(
            cx, wp_out, nullptr, hx_act, out + offs[1], 0, 0.5f);
    } else {
        // fallback: f32-source path (same numerics).
        conv_k3<64, 16, 4, 2, 4, 2, 32, true><<<dim3(2048), blk, 0, stream>>>(
            x, wp_out, nullptr, nullptr, out + offs[0], 0, 0.5f);

        conv_k2<32, 16, 2, 1, 4, 2, true, 64, false><<<dim3(1024), blk, 0, stream>>>(
            x, wp_c0, y_buf, nullptr, 1.0f);
        conv_k3<32, 16, 2, 2, 2, 4, 64, false><<<dim3(512), blk, 0, stream>>>(
            y_buf, wp_r0, nullptr, t_buf, nullptr, 1, 1.0f);
        conv_k3<32, 16, 2, 2, 2, 4, 64, false><<<dim3(512), blk, 0, stream>>>(
            t_buf, wp_r1, y_buf, y_buf, nullptr, 0, 1.0f);
        conv_k3<32, 16, 2, 2, 2, 4, 64, false><<<dim3(512), blk, 0, stream>>>(
            y_buf, wp_c1, nullptr, cx, nullptr, 0, 1.0f);
        conv_k2<32, 16, 2, 1, 4, 1, true, 32, true><<<dim3(1024), blk, 0, stream>>>(
            out + offs[0], wp_h, nullptr, cx, 2.0f);
        conv_k3<32, 16, 2, 2, 2, 2, 32, false><<<dim3(512), blk, 0, stream>>>(
            cx, wp_out, nullptr, hx_act, out + offs[1], 0, 0.5f);
    }

    // ---- level 1: 32 -> 16 ----  (small k3s: FUSECH)
    conv_k2<16, 16, 2, 1, 4, 2, false, 64, false><<<dim3(128), blk, 0, stream>>>(
        cx, wp_c0, y_buf, nullptr, 1.0f);
    conv_k3<16, 16, 2, 1, 1, 4, 64, false, true><<<dim3(128), blk, 0, stream>>>(
        y_buf, wp_r0, nullptr, t_buf, nullptr, 1, 1.0f);
    conv_k3<16, 16, 2, 1, 1, 4, 64, false, true><<<dim3(128), blk, 0, stream>>>(
        t_buf, wp_r1, y_buf, y_buf, nullptr, 0, 1.0f);
    conv_k3<16, 16, 2, 1, 1, 4, 64, false, true><<<dim3(128), blk, 0, stream>>>(
        y_buf, wp_c1, nullptr, cx, nullptr, 0, 1.0f);
    conv_k2<16, 16, 2, 1, 4, 1, false, 32, true><<<dim3(128), blk, 0, stream>>>(
        hx_act, wp_h, nullptr, cx, 1.0f);
    conv_k3<16, 16, 2, 1, 1, 2, 32, false, true><<<dim3(128), blk, 0, stream>>>(
        cx, wp_out, nullptr, hx_act, out + offs[2], 0, 0.5f);

    // ---- level 2: 16 -> 8 ----  (small k3s: FUSECH)
    conv_k2<8, 8, 4, 1, 4, 2, false, 64, false><<<dim3(16), blk, 0, stream>>>(
        cx, wp_c0, y_buf, nullptr, 1.0f);
    conv_k3<8, 8, 4, 1, 1, 4, 64, false, true><<<dim3(16), blk, 0, stream>>>(
        y_buf, wp_r0, nullptr, t_buf, nullptr, 1, 1.0f);
    conv_k3<8, 8, 4, 1, 1, 4, 64, false, true><<<dim3(16), blk, 0, stream>>>(
        t_buf, wp_r1, y_buf, y_buf, nullptr, 0, 1.0f);
    conv_k3<8, 8, 4, 1, 1, 4, 64, false, true><<<dim3(16), blk, 0, stream>>>(
        y_buf, wp_c1, nullptr, cx, nullptr, 0, 1.0f);
    conv_k2<8, 8, 4, 1, 4, 1, false, 32, true><<<dim3(16), blk, 0, stream>>>(
        hx_act, wp_h, nullptr, cx, 1.0f);
    conv_k3<8, 8, 4, 1, 1, 2, 32, false, true><<<dim3(16), blk, 0, stream>>>(
        cx, wp_out, nullptr, nullptr, out + offs[3], 0, 0.5f);
}

// Round 14
// 341.452 us; speedup vs baseline: 1.0809x; 1.0629x over previous
//
#include <hip/hip_runtime.h>
#include <math.h>

// ---------------------------------------------------------------------------
// Round 19: byte-exact R14/R10 restore (measured 341.5us, reproduced
// 342.2us — session best). The R17/R18 merged-kernel experiment hit
// "container failed twice" on two consecutive rounds with identical
// source (bracketed by successful runs of other sources) — either broker
// flakiness or the dyn-LDS dual-personality kernel kills the container;
// not distinguishable from here, so bank the proven state instead of a
// third gamble. Session ledger: 563.9 -> 341.5us via pack-once f16
// staging (R7), single-f16-acts (R8), 16x4x4 big tile (R9), single-MFMA
// f16xf16 (R10). Eight structural experiments since all lost to this
// state (post-mortems in round notes): remaining time is distributed
// small-dispatch latency that HIP-level restructuring worsens.
// absmax 0.015625 (3.3x margin vs 0.052 gate).
// ---------------------------------------------------------------------------

typedef _Float16 f16;
typedef _Float16 f16x8 __attribute__((ext_vector_type(8)));
typedef _Float16 f16x4 __attribute__((ext_vector_type(4)));
typedef float    f32x4 __attribute__((ext_vector_type(4)));

#define PIX 40   // f16 per LDS pixel: 32 payload + 8 pad (80B, 16B-aligned)

// ---- weight packing — single f16 plane ----
__device__ inline void pack_one(const float* __restrict__ w, f16* __restrict__ wp,
                                int Cin, int taps, int CH, int NMT, int e, int lane)
{
    const int gmt = e % NMT;
    const int h   = (e / NMT) % CH;
    const int tap = e / (NMT * CH);
    const int cout = gmt * 16 + (lane & 15);
    const int cin0 = h * 32 + ((lane >> 4) & 3) * 8;
    f16x8 v;
    for (int j = 0; j < 8; ++j)
        v[j] = (f16)w[((size_t)cout * Cin + cin0 + j) * taps + tap];
    *(f16x8*)&wp[((size_t)e * 64 + lane) * 8] = v;
}

// One launch: blocks [0,213) pack all 6 weights (4 entries/block),
// blocks [213,...) pack x f32 [64][64^3] -> f16 [pos][ch] (if x16 != null).
__global__ __launch_bounds__(256) void pack_fused(
    const float* wh, const float* wc0, const float* wr0,
    const float* wr1, const float* wc1, const float* wout,
    f16* ph, f16* pc0, f16* pr0, f16* pr1, f16* pc1, f16* pout,
    const float* x, f16* x16)
{
    const int b = blockIdx.x;
    if (b < 213) {
        const int e    = b * 4 + (threadIdx.x >> 6);
        const int lane = threadIdx.x & 63;
        if      (e < 32)   pack_one(wh,   ph,   32, 8,  1, 4, e,        lane);
        else if (e < 96)   pack_one(wc0,  pc0,  64, 8,  2, 4, e - 32,   lane);
        else if (e < 312)  pack_one(wr0,  pr0,  64, 27, 2, 4, e - 96,   lane);
        else if (e < 528)  pack_one(wr1,  pr1,  64, 27, 2, 4, e - 312,  lane);
        else if (e < 744)  pack_one(wc1,  pc1,  64, 27, 2, 4, e - 528,  lane);
        else               pack_one(wout, pout, 64, 27, 2, 2, e - 744,  lane);
    } else if (x16) {
        const int i   = (b - 213) * 256 + threadIdx.x;   // [0, 64^3*8)
        const int g   = (i >> 3) & 7;
        const int pos = ((i >> 6) << 3) | (i & 7);
        const float* src = x + (size_t)g * 8 * 262144 + pos;
        f16x8 hi;
#pragma unroll
        for (int j = 0; j < 8; ++j) hi[j] = (f16)src[(size_t)j * 262144];
        *(f16x8*)&x16[(size_t)pos * 64 + g * 8] = hi;
    }
}

// Octant swizzle for XCD L2 locality.
template<int NXC, int NYC, int NZC>
__device__ inline void tile_coords(int bid, int& xc, int& yb, int& zb)
{
    if ((NXC % 2 == 0) && (NYC % 2 == 0) && (NZC % 2 == 0) && (NXC*NYC*NZC >= 64)) {
        const int o = bid & 7, j = bid >> 3;
        constexpr int HX = NXC / 2, HY = NYC / 2;
        xc = (j % HX) + (o & 1) * HX;
        yb = ((j / HX) % HY) + ((o >> 1) & 1) * HY;
        zb = (j / (HX * HY)) + (o >> 2) * (NZC / 2);
    } else {
        xc = bid % NXC;
        yb = (bid / NXC) % NYC;
        zb = bid / (NXC * NYC);
    }
}

// ---------------- k3 s1 SAME conv, Cin=64 ----------------
// 4 waves = 2 n-groups x 2 m-groups. Each wave: NT n-tiles (16 px each),
// MTW = NMT/2 m-tiles. Block px = 2*NT*16 = TX*TY*TZ.
template<int S, int TX, int TY, int TZ, int NT, int NMT, int ACT_C, bool SRCF32>
__global__ __launch_bounds__(256) void conv_k3(
    const void* __restrict__ in_, const f16* __restrict__ wp,
    const f16* __restrict__ addsrc, f16* __restrict__ act_out,
    float* __restrict__ f32_out, int relu, float scale)
{
    constexpr int S2 = S * S, S3 = S2 * S;
    constexpr int XP = TX + 2, YP = TY + 2, ZP = TZ + 2;
    constexpr int NPX = XP * YP * ZP;
    constexpr int NXC = S / TX, NYC = S / TY, NZC = S / TZ;
    constexpr int CH = 2;
    constexpr int MTW = NMT / 2;
    static_assert(TX * TY * TZ == 2 * NT * 16, "tile/wave mismatch");
    __shared__ __align__(16) f16 sm[NPX * PIX];

    int xc, yb, zb;
    tile_coords<NXC, NYC, NZC>(blockIdx.x, xc, yb, zb);
    const int x0 = xc * TX, y0 = yb * TY, z0 = zb * TZ;

    const int tid  = threadIdx.x;
    const int lane = tid & 63;
    const int wave = tid >> 6;
    const int i15  = lane & 15, quad = (lane >> 4) & 3;
    const int ng = wave & 1, mh = wave >> 1;

    int lx[NT], ly[NT], lz[NT];
#pragma unroll
    for (int t = 0; t < NT; ++t) {
        const int p = (ng * NT + t) * 16 + i15;
        lx[t] = p % TX; ly[t] = (p / TX) % TY; lz[t] = p / (TX * TY);
    }

    f32x4 acc[NT][MTW];
#pragma unroll
    for (int t = 0; t < NT; ++t)
#pragma unroll
        for (int m = 0; m < MTW; ++m) { f32x4 z = {0.f,0.f,0.f,0.f}; acc[t][m] = z; }

    for (int h = 0; h < CH; ++h) {
        __syncthreads();
        if (SRCF32) {
            const float* src = (const float*)in_;
            for (int it = tid; it < NPX * 4; it += 256) {
                const int xp = it % XP;
                const int rem = it / XP;
                const int row = rem % (YP * ZP);
                const int cc = rem / (YP * ZP);       // 0..3
                const int zr = row / YP, yr = row % YP;
                const int pz = z0 + zr - 1, py = y0 + yr - 1, px = x0 + xp - 1;
                const bool ok = (unsigned)pz < (unsigned)S && (unsigned)py < (unsigned)S
                             && (unsigned)px < (unsigned)S;
                f16x8 v;
                if (ok) {
                    const size_t pos = (size_t)(pz * S2 + py * S + px);
                    const int cbase = h * 32 + cc * 8;
#pragma unroll
                    for (int j = 0; j < 8; ++j)
                        v[j] = (f16)src[(size_t)(cbase + j) * S3 + pos];
                } else {
#pragma unroll
                    for (int j = 0; j < 8; ++j) v[j] = (f16)0.f;
                }
                *(f16x8*)&sm[(row * XP + xp) * PIX + cc * 8] = v;
            }
        } else {
            const f16* src = (const f16*)in_;
            for (int it = tid; it < NPX * 4; it += 256) {
                const int cc = it & 3;
                const int pxl = it >> 2;
                const int xp = pxl % XP;
                const int row = pxl / XP;
                const int zr = row / YP, yr = row % YP;
                const int pz = z0 + zr - 1, py = y0 + yr - 1, px = x0 + xp - 1;
                const bool ok = (unsigned)pz < (unsigned)S && (unsigned)py < (unsigned)S
                             && (unsigned)px < (unsigned)S;
                f16x8 v;
                if (ok) {
                    const size_t pos = (size_t)(pz * S2 + py * S + px);
                    v = *(const f16x8*)&src[pos * 64 + h * 32 + cc * 8];
                } else {
#pragma unroll
                    for (int j = 0; j < 8; ++j) v[j] = (f16)0.f;
                }
                *(f16x8*)&sm[(row * XP + xp) * PIX + cc * 8] = v;
            }
        }
        __syncthreads();

        for (int dz = 0; dz < 3; ++dz) {
#pragma unroll
            for (int dy = 0; dy < 3; ++dy) {
#pragma unroll
                for (int dx = 0; dx < 3; ++dx) {
                    const int tap = dz * 9 + dy * 3 + dx;
                    f16x8 aw[MTW];
#pragma unroll
                    for (int m = 0; m < MTW; ++m) {
                        const int gm = mh * MTW + m;
                        aw[m] = *(const f16x8*)&wp[((size_t)((tap * CH + h) * NMT + gm)) * 512 + lane * 8];
                    }
#pragma unroll
                    for (int t = 0; t < NT; ++t) {
                        const int pix = ((lz[t] + dz) * YP + ly[t] + dy) * XP + lx[t] + dx;
                        const f16x8 bh = *(const f16x8*)&sm[pix * PIX + quad * 8];
#pragma unroll
                        for (int m = 0; m < MTW; ++m)
                            acc[t][m] = __builtin_amdgcn_mfma_f32_16x16x32_f16(aw[m], bh, acc[t][m], 0, 0, 0);
                    }
                }
            }
        }
    }

    // epilogue: C/D layout col(=pos)=lane&15, row(=cout_local)=quad*4+r
#pragma unroll
    for (int t = 0; t < NT; ++t) {
        const int pg = (z0 + lz[t]) * S2 + (y0 + ly[t]) * S + x0 + lx[t];
#pragma unroll
        for (int m = 0; m < MTW; ++m) {
            const int gm = mh * MTW + m;
            float a[4];
#pragma unroll
            for (int r = 0; r < 4; ++r) a[r] = acc[t][m][r];
            if (addsrc) {
                const f16x4 ah = *(const f16x4*)&addsrc[(size_t)pg * 64 + gm * 16 + quad * 4];
#pragma unroll
                for (int r = 0; r < 4; ++r) a[r] += (float)ah[r];
            }
            if (relu) {
#pragma unroll
                for (int r = 0; r < 4; ++r) a[r] = fmaxf(a[r], 0.f);
            }
            if (act_out) {
                f16x4 hi;
#pragma unroll
                for (int r = 0; r < 4; ++r) hi[r] = (f16)a[r];
                *(f16x4*)&act_out[(size_t)pg * ACT_C + gm * 16 + quad * 4] = hi;
            }
            if (f32_out) {
#pragma unroll
                for (int r = 0; r < 4; ++r)
                    f32_out[(size_t)(gm * 16 + quad * 4 + r) * S3 + pg] = a[r] * scale;
            }
        }
    }
}

// ---------------- k2 s2 VALID conv ----------------
// 32 out px per block (2 ngroups x 16), m-split. Even/odd x-interleaved LDS
// slots keep stride-2 reads conflict-free.
template<int So, int TX, int TY, int TZ, int NMT, int CH, bool SRCF32, int SRC_C, bool GATE>
__global__ __launch_bounds__(256) void conv_k2(
    const void* __restrict__ in_, const f16* __restrict__ wp,
    f16* __restrict__ act_out, f16* __restrict__ cx, float src_scale)
{
    constexpr int So2 = So * So;
    constexpr int Si = 2 * So, Si2 = Si * Si, Si3 = Si2 * Si;
    constexpr int XI = 2 * TX, YI = 2 * TY, ZI = 2 * TZ;
    constexpr int NPX = XI * YI * ZI;
    constexpr int NXC = So / TX, NYC = So / TY, NZC = So / TZ;
    constexpr int MTW = NMT / 2;
    static_assert(TX * TY * TZ == 32, "k2 tile must be 32 px");
    __shared__ __align__(16) f16 sm[NPX * PIX];

    int xc, yb, zb;
    tile_coords<NXC, NYC, NZC>(blockIdx.x, xc, yb, zb);
    const int x0 = xc * TX, y0 = yb * TY, z0 = zb * TZ;

    const int tid  = threadIdx.x;
    const int lane = tid & 63;
    const int wave = tid >> 6;
    const int i15  = lane & 15, quad = (lane >> 4) & 3;
    const int nt = wave & 1, mh = wave >> 1;
    const int p = nt * 16 + i15;
    const int lx = p % TX, ly = (p / TX) % TY, lz = p / (TX * TY);

    f32x4 acc[MTW];
#pragma unroll
    for (int m = 0; m < MTW; ++m) { f32x4 z = {0.f,0.f,0.f,0.f}; acc[m] = z; }

    for (int h = 0; h < CH; ++h) {
        __syncthreads();
        if (SRCF32) {
            const float* src = (const float*)in_;
            for (int it = tid; it < NPX * 4; it += 256) {
                const int xp = it % XI;
                const int rem = it / XI;
                const int row = rem % (YI * ZI);
                const int cc = rem / (YI * ZI);       // 0..3
                const int zr = row / YI, yr = row % YI;
                const size_t pos = (size_t)((z0 * 2 + zr) * Si2 + (y0 * 2 + yr) * Si + x0 * 2 + xp);
                const int cbase = h * 32 + cc * 8;
                f16x8 v;
#pragma unroll
                for (int j = 0; j < 8; ++j)
                    v[j] = (f16)(src[(size_t)(cbase + j) * Si3 + pos] * src_scale);
                const int slot = (xp >> 1) + (xp & 1) * TX;
                *(f16x8*)&sm[(row * XI + slot) * PIX + cc * 8] = v;
            }
        } else {
            const f16* src = (const f16*)in_;
            for (int it = tid; it < NPX * 4; it += 256) {
                const int cc = it & 3;
                const int pxl = it >> 2;
                const int xp = pxl % XI;
                const int row = pxl / XI;
                const int zr = row / YI, yr = row % YI;
                const size_t pos = (size_t)((z0 * 2 + zr) * Si2 + (y0 * 2 + yr) * Si + x0 * 2 + xp);
                f16x8 v = *(const f16x8*)&src[pos * SRC_C + h * 32 + cc * 8];
                const int slot = (xp >> 1) + (xp & 1) * TX;
                *(f16x8*)&sm[(row * XI + slot) * PIX + cc * 8] = v;
            }
        }
        __syncthreads();

#pragma unroll
        for (int dz = 0; dz < 2; ++dz) {
#pragma unroll
            for (int dy = 0; dy < 2; ++dy) {
#pragma unroll
                for (int dx = 0; dx < 2; ++dx) {
                    const int tap = dz * 4 + dy * 2 + dx;
                    const int pix = ((2 * lz + dz) * YI + 2 * ly + dy) * XI + lx + dx * TX;
                    const f16x8 bh = *(const f16x8*)&sm[pix * PIX + quad * 8];
#pragma unroll
                    for (int m = 0; m < MTW; ++m) {
                        const int gm = mh * MTW + m;
                        const f16x8 aw = *(const f16x8*)&wp[((size_t)((tap * CH + h) * NMT + gm)) * 512 + lane * 8];
                        acc[m] = __builtin_amdgcn_mfma_f32_16x16x32_f16(aw, bh, acc[m], 0, 0, 0);
                    }
                }
            }
        }
    }

    const int pg = (z0 + lz) * So2 + (y0 + ly) * So + x0 + lx;
#pragma unroll
    for (int m = 0; m < MTW; ++m) {
        const int gm = mh * MTW + m;
        if (GATE) {
            f16x4 c4 = *(const f16x4*)&cx[(size_t)pg * 64 + gm * 16 + quad * 4];
            f16x4 n4;
#pragma unroll
            for (int r = 0; r < 4; ++r) {
                const float g = 1.0f / (1.0f + expf(-fmaxf(acc[m][r], 0.f)));
                n4[r] = (f16)((float)c4[r] * g);
            }
            *(f16x4*)&cx[(size_t)pg * 64 + gm * 16 + quad * 4] = n4;
        } else {
            f16x4 hi;
#pragma unroll
            for (int r = 0; r < 4; ++r) hi[r] = (f16)fmaxf(acc[m][r], 0.f); // ConvBlock relu
            *(f16x4*)&act_out[(size_t)pg * 64 + gm * 16 + quad * 4] = hi;
        }
    }
}

extern "C" void kernel_launch(void* const* d_in, const int* in_sizes, int n_in,
                              void* d_out, int out_size, void* d_ws, size_t ws_size,
                              hipStream_t stream)
{
    const float* x     = (const float*)d_in[0];
    const float* w_h   = (const float*)d_in[1];
    const float* w_c0  = (const float*)d_in[2];
    const float* w_r0  = (const float*)d_in[3];
    const float* w_r1  = (const float*)d_in[4];
    const float* w_c1  = (const float*)d_in[5];
    const float* w_out = (const float*)d_in[6];
    float* out = (float*)d_out;
    f16* ws = (f16*)d_ws;

    // ws layout (f16 units) — single-plane weights
    size_t o = 0;
    f16* wp_h   = ws + o; o += (size_t)8 * 1 * 4 * 512;     // 32 entries
    f16* wp_c0  = ws + o; o += (size_t)8 * 2 * 4 * 512;     // 64
    f16* wp_r0  = ws + o; o += (size_t)27 * 2 * 4 * 512;    // 216
    f16* wp_r1  = ws + o; o += (size_t)27 * 2 * 4 * 512;    // 216
    f16* wp_c1  = ws + o; o += (size_t)27 * 2 * 4 * 512;    // 216
    f16* wp_out = ws + o; o += (size_t)27 * 2 * 2 * 512;    // 108
    const size_t ABUF = (size_t)32 * 32 * 32 * 64;          // C=64 act, 32^3
    f16* y_buf  = ws + o; o += ABUF;
    f16* t_buf  = ws + o; o += ABUF;
    f16* cx     = ws + o; o += ABUF;
    f16* hx_act = ws + o; o += (size_t)32 * 32 * 32 * 32;   // C=32 act, 32^3
    // fast-path buffers
    f16* x16    = ws + o; const size_t o_x16  = o + (size_t)64 * 64 * 64 * 64;
    f16* hx0a   = ws + o_x16; const size_t o_end = o_x16 + (size_t)64 * 64 * 64 * 32;
    const bool fast = ws_size >= o_end * sizeof(f16);

    size_t offs[4];
    offs[0] = 0;
    offs[1] = offs[0] + (size_t)32 * 64 * 64 * 64;
    offs[2] = offs[1] + (size_t)32 * 32 * 32 * 32;
    offs[3] = offs[2] + (size_t)32 * 16 * 16 * 16;

    const dim3 blk(256);

    // one merged pack launch: 213 weight blocks (+8192 x blocks on fast path)
    pack_fused<<<dim3(fast ? 8405 : 213), blk, 0, stream>>>(
        w_h, w_c0, w_r0, w_r1, w_c1, w_out,
        wp_h, wp_c0, wp_r0, wp_r1, wp_c1, wp_out,
        x, fast ? x16 : nullptr);

    if (fast) {
        // hx0 = 0.5 * conv_out(x) @64^3. Tile 16x4x4 (NT=8), f16 src,
        // also emit unscaled hx0 act (C=32) for the level-0 gate.
        conv_k3<64, 16, 4, 4, 8, 2, 32, false><<<dim3(1024), blk, 0, stream>>>(
            x16, wp_out, nullptr, hx0a, out + offs[0], 0, 0.5f);

        // ---- level 0: 64 -> 32 ----
        conv_k2<32, 16, 2, 1, 4, 2, false, 64, false><<<dim3(1024), blk, 0, stream>>>(
            x16, wp_c0, y_buf, nullptr, 1.0f);
        conv_k3<32, 16, 2, 2, 2, 4, 64, false><<<dim3(512), blk, 0, stream>>>(
            y_buf, wp_r0, nullptr, t_buf, nullptr, 1, 1.0f);
        conv_k3<32, 16, 2, 2, 2, 4, 64, false><<<dim3(512), blk, 0, stream>>>(
            t_buf, wp_r1, y_buf, y_buf, nullptr, 0, 1.0f);
        conv_k3<32, 16, 2, 2, 2, 4, 64, false><<<dim3(512), blk, 0, stream>>>(
            y_buf, wp_c1, nullptr, cx, nullptr, 0, 1.0f);
        conv_k2<32, 16, 2, 1, 4, 1, false, 32, true><<<dim3(1024), blk, 0, stream>>>(
            hx0a, wp_h, nullptr, cx, 1.0f);
        conv_k3<32, 16, 2, 2, 2, 2, 32, false><<<dim3(512), blk, 0, stream>>>(
            cx, wp_out, nullptr, hx_act, out + offs[1], 0, 0.5f);
    } else {
        // fallback: f32-source path (same numerics).
        conv_k3<64, 16, 4, 2, 4, 2, 32, true><<<dim3(2048), blk, 0, stream>>>(
            x, wp_out, nullptr, nullptr, out + offs[0], 0, 0.5f);

        conv_k2<32, 16, 2, 1, 4, 2, true, 64, false><<<dim3(1024), blk, 0, stream>>>(
            x, wp_c0, y_buf, nullptr, 1.0f);
        conv_k3<32, 16, 2, 2, 2, 4, 64, false><<<dim3(512), blk, 0, stream>>>(
            y_buf, wp_r0, nullptr, t_buf, nullptr, 1, 1.0f);
        conv_k3<32, 16, 2, 2, 2, 4, 64, false><<<dim3(512), blk, 0, stream>>>(
            t_buf, wp_r1, y_buf, y_buf, nullptr, 0, 1.0f);
        conv_k3<32, 16, 2, 2, 2, 4, 64, false><<<dim3(512), blk, 0, stream>>>(
            y_buf, wp_c1, nullptr, cx, nullptr, 0, 1.0f);
        conv_k2<32, 16, 2, 1, 4, 1, true, 32, true><<<dim3(1024), blk, 0, stream>>>(
            out + offs[0], wp_h, nullptr, cx, 2.0f);
        conv_k3<32, 16, 2, 2, 2, 2, 32, false><<<dim3(512), blk, 0, stream>>>(
            cx, wp_out, nullptr, hx_act, out + offs[1], 0, 0.5f);
    }

    // ---- level 1: 32 -> 16 ----  (32-px tiles: grid 128)
    conv_k2<16, 16, 2, 1, 4, 2, false, 64, false><<<dim3(128), blk, 0, stream>>>(
        cx, wp_c0, y_buf, nullptr, 1.0f);
    conv_k3<16, 16, 2, 1, 1, 4, 64, false><<<dim3(128), blk, 0, stream>>>(
        y_buf, wp_r0, nullptr, t_buf, nullptr, 1, 1.0f);
    conv_k3<16, 16, 2, 1, 1, 4, 64, false><<<dim3(128), blk, 0, stream>>>(
        t_buf, wp_r1, y_buf, y_buf, nullptr, 0, 1.0f);
    conv_k3<16, 16, 2, 1, 1, 4, 64, false><<<dim3(128), blk, 0, stream>>>(
        y_buf, wp_c1, nullptr, cx, nullptr, 0, 1.0f);
    conv_k2<16, 16, 2, 1, 4, 1, false, 32, true><<<dim3(128), blk, 0, stream>>>(
        hx_act, wp_h, nullptr, cx, 1.0f);
    conv_k3<16, 16, 2, 1, 1, 2, 32, false><<<dim3(128), blk, 0, stream>>>(
        cx, wp_out, nullptr, hx_act, out + offs[2], 0, 0.5f);

    // ---- level 2: 16 -> 8 ----  (32-px tiles: grid 16)
    conv_k2<8, 8, 4, 1, 4, 2, false, 64, false><<<dim3(16), blk, 0, stream>>>(
        cx, wp_c0, y_buf, nullptr, 1.0f);
    conv_k3<8, 8, 4, 1, 1, 4, 64, false><<<dim3(16), blk, 0, stream>>>(
        y_buf, wp_r0, nullptr, t_buf, nullptr, 1, 1.0f);
    conv_k3<8, 8, 4, 1, 1, 4, 64, false><<<dim3(16), blk, 0, stream>>>(
        t_buf, wp_r1, y_buf, y_buf, nullptr, 0, 1.0f);
    conv_k3<8, 8, 4, 1, 1, 4, 64, false><<<dim3(16), blk, 0, stream>>>(
        y_buf, wp_c1, nullptr, cx, nullptr, 0, 1.0f);
    conv_k2<8, 8, 4, 1, 4, 1, false, 32, true><<<dim3(16), blk, 0, stream>>>(
        hx_act, wp_h, nullptr, cx, 1.0f);
    conv_k3<8, 8, 4, 1, 1, 2, 32, false><<<dim3(16), blk, 0, stream>>>(
        cx, wp_out, nullptr, nullptr, out + offs[3], 0, 0.5f);
}